// Round 10
// baseline (223.912 us; speedup 1.0000x reference)
//
#include <hip/hip_runtime.h>
#include <cmath>

// ---------------------------------------------------------------------------
// DistanceAwareMultiheadAttention  (N=1536, E=49152, D=512, H=8, DH=64)
//
// Round 10:
//  - REVERT flash epilogue to r8 Opart/Lpart + combine (r9's atomic-Obuf RMW
//    cost +8MB traffic, 45.8 -> 54us). Lesson: streams beat atomics.
//  - flash grid XCD-swizzle: dim3(s=4, qt=96, h=8) -> linear id = h*384+qt*4+s,
//    384 % 8 == 0 puts all 8 heads of a (qt,s) on ONE XCD class -> eid16
//    slices disjoint per XCD (4.7MB total HBM instead of ~8x re-fetch).
//  - rel dense 9.4MB zero-init ELIMINATED: setup zeroes only edge positions
//    (and writes idxn; dtype detect moved there).
//  - Q/K f32 never materialized: delta_k gathers from bf16 hi/lo packs
//    (Q un-scaled by 4; exact). qkvm sheds 6.3MB write.
// ---------------------------------------------------------------------------

constexpr int Nn  = 1536;
constexpr int Dd  = 512;
constexpr int Hh  = 8;
constexpr int DHd = 64;
constexpr int SPLITS = 4;
constexpr float SCALE_F = 362.03867196751236f;   // 256*sqrt(2)
constexpr float M0 = 8.0f;                       // fixed softmax exp offset

typedef float f4 __attribute__((ext_vector_type(4)));
typedef int   i4 __attribute__((ext_vector_type(4)));
typedef unsigned short us4 __attribute__((ext_vector_type(4)));
typedef __attribute__((ext_vector_type(4))) float f32x4;
typedef __attribute__((ext_vector_type(8))) short bf16x8;

__device__ inline unsigned short bf16_rne(float x) {
    unsigned u = __float_as_uint(x);
    unsigned r = u + 0x7fff + ((u >> 16) & 1);
    return (unsigned short)(r >> 16);
}
__device__ inline float bf16_tof(unsigned short h) {
    return __uint_as_float(((unsigned)h) << 16);
}
__device__ inline unsigned f2ord(float x) {
    unsigned b = __float_as_uint(x);
    return (b & 0x80000000u) ? ~b : (b | 0x80000000u);
}

// ---- setup: feat/W pack + eid16 init + qodd/kodd/ordmax init + edge prep ---
// blocks: [0,384) feat pack | [384,768) W pack | [768,3072) eid16 init
// | [3072,3096) qodd/kodd=0 | [3096,3098) ordmax | [3098,3098+EB) edge prep
__global__ __launch_bounds__(256) void setup_k(
    const float* __restrict__ feat,
    const float* __restrict__ Wq, const float* __restrict__ Wk, const float* __restrict__ Wv,
    const int* __restrict__ raw,
    unsigned short* __restrict__ pFh, unsigned short* __restrict__ pFl,
    unsigned short* __restrict__ pWh, unsigned short* __restrict__ pWl,
    unsigned short* __restrict__ eid16, float* __restrict__ rel,
    int* __restrict__ idxn, float* __restrict__ qkodd,
    unsigned* __restrict__ ordmax, int E)
{
    const int b = blockIdx.x, tid = threadIdx.x;
    if (b < 768) {
        int type = (b >= 384);
        int tg = (type ? (b - 384) : b) * 256 + tid;
        int L = tg & 63;
        int kc = (tg >> 6) & 15;
        int t10 = tg >> 10;
        const float* src;
        unsigned short *oh, *ol;
        int row, col;
        if (type == 0) {
            src = feat; oh = pFh; ol = pFl;
            row = t10 * 16 + (L & 15);
            col = kc * 32 + (L >> 4) * 8;
        } else {
            int z = t10 >> 5, nt = t10 & 31;
            src = (z == 0) ? Wq : (z == 1) ? Wk : Wv;
            oh = pWh; ol = pWl;
            row = nt * 16 + (L & 15);
            col = kc * 32 + (L >> 4) * 8;
        }
        f4 a = *(const f4*)(src + (size_t)row * Dd + col);
        f4 bb = *(const f4*)(src + (size_t)row * Dd + col + 4);
        float x[8];
        #pragma unroll
        for (int j = 0; j < 4; ++j) { x[j] = a[j]; x[4 + j] = bb[j]; }
        unsigned short hs[8], ls[8];
        #pragma unroll
        for (int j = 0; j < 8; ++j) {
            hs[j] = bf16_rne(x[j]);
            ls[j] = bf16_rne(x[j] - bf16_tof(hs[j]));
        }
        *(bf16x8*)(oh + (size_t)tg * 8) = *(bf16x8*)hs;
        *(bf16x8*)(ol + (size_t)tg * 8) = *(bf16x8*)ls;
    } else if (b < 3072) {
        size_t idx = (size_t)(b - 768) * 256 + tid;
        *(us4*)(eid16 + idx * 4) = (us4){0xFFFFu, 0xFFFFu, 0xFFFFu, 0xFFFFu};
    } else if (b < 3096) {
        size_t idx = (size_t)(b - 3072) * 256 + tid;
        *(f4*)(qkodd + idx * 4) = (f4){0.f, 0.f, 0.f, 0.f};
    } else if (b < 3098) {
        int idx = (b - 3096) * 256 + tid;
        ordmax[idx] = 0x007FFFFFu;  // encode(-inf)
    } else {
        int e = (b - 3098) * 256 + tid;
        if (e < E) {
            int acc = 0;
            #pragma unroll
            for (int i = 0; i < 16; ++i) acc |= raw[2 * i + 1];
            int s, t;
            if (acc == 0) { s = raw[2 * e]; t = raw[2 * (E + e)]; }   // int64
            else          { s = raw[e];     t = raw[E + e]; }          // int32
            idxn[e] = s; idxn[E + e] = t;
            rel[(size_t)s * Nn + t] = 0.f;   // zero only edge positions
        }
    }
}

// --------- QKV projection, MFMA, kc-pipelined, fused pack + odd-sums --------
__global__ __launch_bounds__(256) void qkvm_k(
    const unsigned short* __restrict__ pFh, const unsigned short* __restrict__ pFl,
    const unsigned short* __restrict__ pWh, const unsigned short* __restrict__ pWl,
    const float* __restrict__ bq, const float* __restrict__ bk, const float* __restrict__ bv,
    float* __restrict__ qodd, float* __restrict__ kodd,
    unsigned short* __restrict__ pQh, unsigned short* __restrict__ pQl,
    unsigned short* __restrict__ pKh, unsigned short* __restrict__ pKl,
    unsigned short* __restrict__ pVh, unsigned short* __restrict__ pVl)
{
    const int z = blockIdx.z;
    const float* __restrict__ bias = (z == 0) ? bq : (z == 1) ? bk : bv;
    const int tid = threadIdx.x;
    const int L = tid & 63, wv = tid >> 6;
    const int l15 = L & 15, quad = L >> 4;
    const int mt0 = blockIdx.y * 4 + (wv & 1) * 2;
    const int nt0 = blockIdx.x * 4 + (wv >> 1) * 2;
    __shared__ float lds[4][32][33];

    f32x4 acc[2][2];
    #pragma unroll
    for (int i = 0; i < 2; ++i)
        #pragma unroll
        for (int j = 0; j < 2; ++j) acc[i][j] = (f32x4){0.f, 0.f, 0.f, 0.f};

    bf16x8 AH[2][2], AL[2][2], BH[2][2], BL[2][2];
    auto loadset = [&](int buf, int kc) {
        #pragma unroll
        for (int i = 0; i < 2; ++i) {
            size_t ao = ((size_t)((mt0 + i) * 16 + kc)) * 512 + L * 8;
            AH[buf][i] = *(const bf16x8*)(pFh + ao);
            AL[buf][i] = *(const bf16x8*)(pFl + ao);
            size_t bo = ((size_t)((z * 32 + nt0 + i) * 16 + kc)) * 512 + L * 8;
            BH[buf][i] = *(const bf16x8*)(pWh + bo);
            BL[buf][i] = *(const bf16x8*)(pWl + bo);
        }
    };
    auto mfmaset = [&](int buf) {
        #pragma unroll
        for (int i = 0; i < 2; ++i)
            #pragma unroll
            for (int j = 0; j < 2; ++j) {
                f32x4 a = acc[i][j];
                a = __builtin_amdgcn_mfma_f32_16x16x32_bf16(AH[buf][i], BH[buf][j], a, 0, 0, 0);
                a = __builtin_amdgcn_mfma_f32_16x16x32_bf16(AH[buf][i], BL[buf][j], a, 0, 0, 0);
                a = __builtin_amdgcn_mfma_f32_16x16x32_bf16(AL[buf][i], BH[buf][j], a, 0, 0, 0);
                a = __builtin_amdgcn_mfma_f32_16x16x32_bf16(AL[buf][i], BL[buf][j], a, 0, 0, 0);
                acc[i][j] = a;
            }
    };

    loadset(0, 0);
    #pragma unroll
    for (int kc = 0; kc < 16; kc += 2) {
        loadset(1, kc + 1);
        mfmaset(0);
        if (kc + 2 < 16) loadset(0, kc + 2);
        mfmaset(1);
    }

    float o_[2][2][4];
    #pragma unroll
    for (int i = 0; i < 2; ++i)
        #pragma unroll
        for (int j = 0; j < 2; ++j) {
            float b = bias[(nt0 + j) * 16 + l15];
            #pragma unroll
            for (int reg = 0; reg < 4; ++reg) o_[i][j][reg] = acc[i][j][reg] + b;
        }
    const int h = blockIdx.x;   // cols [h*64, h*64+64) == head h
    if (z < 2) {
        // odd-col partial row sums -> qodd/kodd
        float* __restrict__ odst = (z == 0) ? qodd : kodd;
        #pragma unroll
        for (int i = 0; i < 2; ++i) {
            #pragma unroll
            for (int reg = 0; reg < 4; ++reg) {
                float v = (l15 & 1) ? (o_[i][0][reg] + o_[i][1][reg]) : 0.f;
                #pragma unroll
                for (int o = 1; o < 16; o <<= 1) v += __shfl_xor(v, o);
                if (l15 == 0) {
                    int row = (mt0 + i) * 16 + quad * 4 + reg;
                    atomicAdd(&odst[row * Hh + h], v);
                }
            }
        }
    }
    #pragma unroll
    for (int i = 0; i < 2; ++i)
        #pragma unroll
        for (int j = 0; j < 2; ++j)
            #pragma unroll
            for (int reg = 0; reg < 4; ++reg)
                lds[wv][i * 16 + quad * 4 + reg][j * 16 + l15] = o_[i][j][reg];
    // single-wave LDS round trip: DS pipe is in-order per wave, no barrier.

    if (z < 2) {
        unsigned short* __restrict__ oh = z ? pKh : pQh;
        unsigned short* __restrict__ ol = z ? pKl : pQl;
        const int kc = wv >> 1;
        const float sc = z ? 1.0f : 0.25f;      // Q pre-scaled (exact pow2)
        #pragma unroll
        for (int i = 0; i < 2; ++i) {
            float x[8]; unsigned short hs[8], ls[8];
            #pragma unroll
            for (int j2 = 0; j2 < 8; ++j2)
                x[j2] = lds[wv][i * 16 + l15][quad * 8 + j2] * sc;
            #pragma unroll
            for (int j2 = 0; j2 < 8; ++j2) {
                hs[j2] = bf16_rne(x[j2]);
                ls[j2] = bf16_rne(x[j2] - bf16_tof(hs[j2]));
            }
            size_t off = ((size_t)((h * 96 + mt0 + i) * 2 + kc)) * 512 + L * 8;
            *(bf16x8*)(oh + off) = *(bf16x8*)hs;
            *(bf16x8*)(ol + off) = *(bf16x8*)ls;
        }
    } else {
        const int rc = blockIdx.y * 2 + (wv & 1);
        #pragma unroll
        for (int dtl = 0; dtl < 2; ++dtl) {
            int dt = (wv >> 1) * 2 + dtl;
            float x[8]; unsigned short hs[8], ls[8];
            #pragma unroll
            for (int j2 = 0; j2 < 8; ++j2)
                x[j2] = lds[wv][quad * 8 + j2][dtl * 16 + l15];
            #pragma unroll
            for (int j2 = 0; j2 < 8; ++j2) {
                hs[j2] = bf16_rne(x[j2]);
                ls[j2] = bf16_rne(x[j2] - bf16_tof(hs[j2]));
            }
            size_t off = ((size_t)((h * 48 + rc) * 4 + dt)) * 512 + L * 8;
            *(bf16x8*)(pVh + off) = *(bf16x8*)hs;
            *(bf16x8*)(pVl + off) = *(bf16x8*)ls;
        }
    }
}

// --------------------------- scatter (idxn precomputed) ---------------------
__global__ __launch_bounds__(256) void scatter_k(
    const int* __restrict__ idxn, const float* __restrict__ attr,
    float* __restrict__ rel, unsigned short* __restrict__ eid16, int E)
{
    int e = blockIdx.x * 256 + threadIdx.x;
    if (e >= E) return;
    int s = idxn[e], t = idxn[E + e];
    size_t off = (size_t)s * Nn + t;
    atomicAdd(rel + off, attr[e] * SCALE_F);
    eid16[off] = (unsigned short)e;  // dup edges: same (s,t) -> same delta
}

// ------------- per-edge, per-head corrections (gather from packs) -----------
// Element (row, c) of X (head h): pX[((h*96+row/16)*2+kc)*512 + (quad*16+(row&15))*8 + j]
// with c = kc*32 + quad*8 + j. Q pack holds 0.25*q -> un-scale by 4 (exact).
__global__ __launch_bounds__(256) void delta_k(
    const int* __restrict__ idxn, const float* __restrict__ rel,
    const unsigned short* __restrict__ pQh, const unsigned short* __restrict__ pQl,
    const unsigned short* __restrict__ pKh, const unsigned short* __restrict__ pKl,
    const float* __restrict__ qodd, const float* __restrict__ kodd,
    float* __restrict__ delta8, int E)
{
    int t = blockIdx.x * 256 + threadIdx.x;
    if (t >= E * Hh) return;
    int e = t >> 3, h = t & 7;
    int qi = idxn[e], ri = idxn[E + e];
    float x = rel[(size_t)qi * Nn + ri];
    float acc = 0.f;
    #pragma unroll
    for (int kc = 0; kc < 2; ++kc) {
        #pragma unroll
        for (int qd = 0; qd < 4; ++qd) {
            size_t qoff = ((size_t)((h * 96 + (qi >> 4)) * 2 + kc)) * 512
                        + (size_t)(qd * 16 + (qi & 15)) * 8;
            size_t koff = ((size_t)((h * 96 + (ri >> 4)) * 2 + kc)) * 512
                        + (size_t)(qd * 16 + (ri & 15)) * 8;
            bf16x8 qh8 = *(const bf16x8*)(pQh + qoff);
            bf16x8 ql8 = *(const bf16x8*)(pQl + qoff);
            bf16x8 kh8 = *(const bf16x8*)(pKh + koff);
            bf16x8 kl8 = *(const bf16x8*)(pKl + koff);
            const int ib = kc * 16 + qd * 4;
            #pragma unroll
            for (int jp = 0; jp < 4; ++jp) {
                float dd = 0.15915494309189535f
                         * __builtin_amdgcn_exp2f(-0.4152410118609203f * (float)(ib + jp));
                float r = x * dd; r -= floorf(r);
                float sv = __builtin_amdgcn_sinf(r), cv = __builtin_amdgcn_cosf(r);
                float qe = 4.f * (bf16_tof((unsigned short)qh8[2 * jp]) +
                                  bf16_tof((unsigned short)ql8[2 * jp]))
                         + bf16_tof((unsigned short)kh8[2 * jp])
                         + bf16_tof((unsigned short)kl8[2 * jp]);
                float qo = 4.f * (bf16_tof((unsigned short)qh8[2 * jp + 1]) +
                                  bf16_tof((unsigned short)ql8[2 * jp + 1]))
                         + bf16_tof((unsigned short)kh8[2 * jp + 1])
                         + bf16_tof((unsigned short)kl8[2 * jp + 1]);
                acc += qe * sv + qo * cv;
            }
        }
    }
    delta8[(size_t)e * Hh + h] = 0.125f * (acc - qodd[qi * Hh + h] - kodd[ri * Hh + h]);
}

// -------- flash attention: no-max softmax, K dbuf, XCD-swizzled grid --------
// grid dim3(4,96,8): s=bx, qt=by, h=bz -> linear id = h*384 + qt*4 + s;
// 384 % 8 == 0 puts all 8 heads of a (qt,s) in one id%8 XCD class so eid16
// rows are fetched once per XCD, not 8x.
__global__ __launch_bounds__(64, 3) void flash8_k(
    const unsigned short* __restrict__ pQh, const unsigned short* __restrict__ pQl,
    const unsigned short* __restrict__ pKh, const unsigned short* __restrict__ pKl,
    const unsigned short* __restrict__ pVh, const unsigned short* __restrict__ pVl,
    const unsigned short* __restrict__ eid16, const float* __restrict__ delta8,
    const float* __restrict__ kodd,
    float* __restrict__ Opart, float* __restrict__ Lpart)
{
    const int s = blockIdx.x, qt = blockIdx.y, h = blockIdx.z;
    const int L = threadIdx.x, quad = L >> 4, l15 = L & 15;
    const int q0 = qt * 16;
    __shared__ unsigned short phi[16][80];
    __shared__ unsigned short plo[16][80];

    bf16x8 qh[2], ql[2];
    #pragma unroll
    for (int kc = 0; kc < 2; ++kc) {
        size_t off = ((size_t)((h * 96 + qt) * 2 + kc)) * 512 + L * 8;
        qh[kc] = *(const bf16x8*)(pQh + off);
        ql[kc] = *(const bf16x8*)(pQl + off);
    }

    f32x4 O[4];
    float lsum[4];
    #pragma unroll
    for (int r = 0; r < 4; ++r) { lsum[r] = 0.f; O[r] = (f32x4){0.f, 0.f, 0.f, 0.f}; }

    const int NT = 24 / SPLITS;
    const int Tbase = s * NT;

    bf16x8 kh0[4], kh1[4], kl0[4], kl1[4];
    {
        const int r0 = Tbase * 64;
        #pragma unroll
        for (int nt = 0; nt < 4; ++nt) {
            size_t b0 = ((size_t)((h * 96 + (r0 >> 4) + nt) * 2)) * 512 + L * 8;
            kh0[nt] = *(const bf16x8*)(pKh + b0);
            kh1[nt] = *(const bf16x8*)(pKh + b0 + 512);
            kl0[nt] = *(const bf16x8*)(pKl + b0);
            kl1[nt] = *(const bf16x8*)(pKl + b0 + 512);
        }
    }

    float kvcur[4], dcur[16];
    {
        const int r0 = Tbase * 64;
        int ecur[16];
        #pragma unroll
        for (int nt = 0; nt < 4; ++nt) {
            kvcur[nt] = 0.125f * kodd[(size_t)(r0 + nt * 16 + l15) * Hh + h];
            #pragma unroll
            for (int reg = 0; reg < 4; ++reg) {
                unsigned short uv = eid16[(size_t)(q0 + quad * 4 + reg) * Nn + r0 + nt * 16 + l15];
                ecur[nt * 4 + reg] = (uv == 0xFFFFu) ? -1 : (int)uv;
            }
        }
        #pragma unroll
        for (int i = 0; i < 16; ++i) {
            int e = ecur[i];
            float d = delta8[(size_t)(e < 0 ? 0 : e) * Hh + h];
            dcur[i] = (e >= 0) ? d : 0.f;
        }
    }

    for (int T = 0; T < NT; ++T) {
        const int r0 = (Tbase + T) * 64;
        const bool more = (T + 1 < NT);

        int   enxt[16];
        float kvnxt[4];
        if (more) {
            const int r1 = r0 + 64;
            #pragma unroll
            for (int nt = 0; nt < 4; ++nt) {
                kvnxt[nt] = 0.125f * kodd[(size_t)(r1 + nt * 16 + l15) * Hh + h];
                #pragma unroll
                for (int reg = 0; reg < 4; ++reg) {
                    unsigned short uv = eid16[(size_t)(q0 + quad * 4 + reg) * Nn + r1 + nt * 16 + l15];
                    enxt[nt * 4 + reg] = (uv == 0xFFFFu) ? -1 : (int)uv;
                }
            }
        }

        bf16x8 vh0[4], vh1[4], vl0[4], vl1[4];
        #pragma unroll
        for (int dt = 0; dt < 4; ++dt) {
            size_t vb = ((size_t)((h * 48 + (r0 >> 5)) * 4 + dt)) * 512 + L * 8;
            vh0[dt] = *(const bf16x8*)(pVh + vb);
            vh1[dt] = *(const bf16x8*)(pVh + vb + 2048);
            vl0[dt] = *(const bf16x8*)(pVl + vb);
            vl1[dt] = *(const bf16x8*)(pVl + vb + 2048);
        }

        f32x4 S[4];
        #pragma unroll
        for (int nt = 0; nt < 4; ++nt) {
            f32x4 a = {0.f, 0.f, 0.f, 0.f};
            a = __builtin_amdgcn_mfma_f32_16x16x32_bf16(qh[0], kh0[nt], a, 0, 0, 0);
            a = __builtin_amdgcn_mfma_f32_16x16x32_bf16(qh[1], kh1[nt], a, 0, 0, 0);
            a = __builtin_amdgcn_mfma_f32_16x16x32_bf16(qh[0], kl0[nt], a, 0, 0, 0);
            a = __builtin_amdgcn_mfma_f32_16x16x32_bf16(qh[1], kl1[nt], a, 0, 0, 0);
            a = __builtin_amdgcn_mfma_f32_16x16x32_bf16(ql[0], kh0[nt], a, 0, 0, 0);
            a = __builtin_amdgcn_mfma_f32_16x16x32_bf16(ql[1], kh1[nt], a, 0, 0, 0);
            S[nt] = a;
        }

        if (more) {
            const int r1 = r0 + 64;
            #pragma unroll
            for (int nt = 0; nt < 4; ++nt) {
                size_t b0 = ((size_t)((h * 96 + (r1 >> 4) + nt) * 2)) * 512 + L * 8;
                kh0[nt] = *(const bf16x8*)(pKh + b0);
                kh1[nt] = *(const bf16x8*)(pKh + b0 + 512);
                kl0[nt] = *(const bf16x8*)(pKl + b0);
                kl1[nt] = *(const bf16x8*)(pKl + b0 + 512);
            }
        }

        #pragma unroll
        for (int reg = 0; reg < 4; ++reg) {
            float p[4];
            #pragma unroll
            for (int nt = 0; nt < 4; ++nt) {
                p[nt] = __expf(S[nt][reg] + kvcur[nt] + dcur[nt * 4 + reg] - M0);
                lsum[reg] += p[nt];
                unsigned short hi = bf16_rne(p[nt]);
                phi[quad * 4 + reg][nt * 16 + l15] = hi;
                plo[quad * 4 + reg][nt * 16 + l15] = bf16_rne(p[nt] - bf16_tof(hi));
            }
        }

        bf16x8 ph[2], pl[2];
        #pragma unroll
        for (int kc2 = 0; kc2 < 2; ++kc2) {
            ph[kc2] = *(const bf16x8*)&phi[l15][kc2 * 32 + quad * 8];
            pl[kc2] = *(const bf16x8*)&plo[l15][kc2 * 32 + quad * 8];
        }

        #pragma unroll
        for (int dt = 0; dt < 4; ++dt) {
            f32x4 a = O[dt];
            a = __builtin_amdgcn_mfma_f32_16x16x32_bf16(ph[0], vh0[dt], a, 0, 0, 0);
            a = __builtin_amdgcn_mfma_f32_16x16x32_bf16(ph[1], vh1[dt], a, 0, 0, 0);
            a = __builtin_amdgcn_mfma_f32_16x16x32_bf16(ph[0], vl0[dt], a, 0, 0, 0);
            a = __builtin_amdgcn_mfma_f32_16x16x32_bf16(ph[1], vl1[dt], a, 0, 0, 0);
            a = __builtin_amdgcn_mfma_f32_16x16x32_bf16(pl[0], vh0[dt], a, 0, 0, 0);
            a = __builtin_amdgcn_mfma_f32_16x16x32_bf16(pl[1], vh1[dt], a, 0, 0, 0);
            O[dt] = a;
        }

        if (more) {
            #pragma unroll
            for (int i = 0; i < 16; ++i) {
                int e = enxt[i];
                float d = delta8[(size_t)(e < 0 ? 0 : e) * Hh + h];
                dcur[i] = (e >= 0) ? d : 0.f;
            }
            #pragma unroll
            for (int nt = 0; nt < 4; ++nt) kvcur[nt] = kvnxt[nt];
        }
    }

    #pragma unroll
    for (int reg = 0; reg < 4; ++reg) {
        #pragma unroll
        for (int o = 1; o < 16; o <<= 1) lsum[reg] += __shfl_xor(lsum[reg], o);
    }

    #pragma unroll
    for (int dt = 0; dt < 4; ++dt)
        #pragma unroll
        for (int reg = 0; reg < 4; ++reg)
            Opart[((size_t)(s * Hh + h) * Nn + q0 + quad * 4 + reg) * 64 + dt * 16 + l15] = O[dt][reg];
    if (l15 == 0) {
        #pragma unroll
        for (int reg = 0; reg < 4; ++reg)
            Lpart[(size_t)(s * Hh + h) * Nn + q0 + quad * 4 + reg] = lsum[reg];
    }
}

// ------- split-K combine + maxpool via ordered-uint atomicMax (512 slots) ---
__global__ __launch_bounds__(256) void combine_mp_k(
    const float* __restrict__ Opart, const float* __restrict__ Lpart,
    unsigned* __restrict__ ordmax)
{
    const int b = blockIdx.x;
    const int t = threadIdx.x;
    const int cg = (t & 127) * 4;
    const int h = cg >> 6, d = cg & 63;
    const int rh = t >> 7;
    f4 mx = {-3.0e38f, -3.0e38f, -3.0e38f, -3.0e38f};
    for (int r = 0; r < 8; ++r) {
        int q = b * 16 + rh * 8 + r;
        float l = 0.f;
        f4 o = {0.f, 0.f, 0.f, 0.f};
        #pragma unroll
        for (int s2 = 0; s2 < SPLITS; ++s2) {
            l += Lpart[(size_t)(s2 * Hh + h) * Nn + q];
            f4 ov = *(const f4*)(Opart + ((size_t)(s2 * Hh + h) * Nn + q) * 64 + d);
            #pragma unroll
            for (int c = 0; c < 4; ++c) o[c] += ov[c];
        }
        float inv = 1.0f / l;
        #pragma unroll
        for (int c = 0; c < 4; ++c) mx[c] = fmaxf(mx[c], o[c] * inv);
    }
    #pragma unroll
    for (int c = 0; c < 4; ++c) atomicMax(&ordmax[cg + c], f2ord(mx[c]));
}

__global__ void decode_k(const unsigned* __restrict__ ordmax, float* __restrict__ outp)
{
    int t = blockIdx.x * 256 + threadIdx.x;
    if (t >= Dd) return;
    unsigned u = ordmax[t];
    outp[t] = (u & 0x80000000u) ? __uint_as_float(u ^ 0x80000000u) : __uint_as_float(~u);
}

// ---------------------------------------------------------------------------
extern "C" void kernel_launch(void* const* d_in, const int* in_sizes, int n_in,
                              void* d_out, int out_size, void* d_ws, size_t ws_size,
                              hipStream_t stream)
{
    const float* feat   = (const float*)d_in[0];
    const int*   rawidx = (const int*)d_in[1];
    const float* attr   = (const float*)d_in[2];
    const float* Wq = (const float*)d_in[4];
    const float* bq = (const float*)d_in[5];
    const float* Wk = (const float*)d_in[6];
    const float* bk = (const float*)d_in[7];
    const float* Wv = (const float*)d_in[8];
    const float* bv = (const float*)d_in[9];
    float* outp = (float*)d_out;
    const int E = in_sizes[2];
    const int EB = (E + 255) / 256;

    const size_t NN_ = (size_t)Nn * Nn;            // 2359296
    const size_t PK_ = (size_t)Hh * 96 * 2 * 512;  // 786432 shorts per pack
    // Prefix dead by flash: pF/pW packs (1,572,864 f-equiv) + rel (2,359,296 f)
    // = 3,932,160 f >= Opart (SPLITS*Hh*Nn*64 = 3,145,728 f). eid16.. stays live.
    float* ws = (float*)d_ws;
    unsigned short* pFh = (unsigned short*)ws;      // 4 x 786432 shorts
    unsigned short* pFl = pFh + PK_;
    unsigned short* pWh = pFl + PK_;
    unsigned short* pWl = pWh + PK_;
    float* rel = (float*)(pWl + PK_);               // 2359296 f (edge-sparse)
    unsigned short* eid16 = (unsigned short*)(rel + NN_);  // 2359296 shorts
    float* delta8 = (float*)(eid16 + NN_);          // E*Hh f
    float* qodd  = delta8 + (size_t)E * Hh;         // Nn*Hh f (zeroed w/ kodd)
    float* kodd  = qodd + (size_t)Nn * Hh;          // Nn*Hh f
    int*   idxn  = (int*)(kodd + (size_t)Nn * Hh);  // 2E ints
    unsigned short* pQh = (unsigned short*)(idxn + 2 * E);
    unsigned short* pQl = pQh + PK_;
    unsigned short* pKh = pQl + PK_;
    unsigned short* pKl = pKh + PK_;
    unsigned short* pVh = pKl + PK_;
    unsigned short* pVl = pVh + PK_;
    float* Lpart = (float*)(pVl + PK_);             // SPLITS*Hh*Nn f
    unsigned* ordmax = (unsigned*)(Lpart + (size_t)SPLITS * Hh * Nn);  // 512 u
    float* Opart = ws;   // overlays pF/pW + rel (dead by flash time)

    setup_k<<<3098 + EB, 256, 0, stream>>>(feat, Wq, Wk, Wv, rawidx,
                                           pFh, pFl, pWh, pWl,
                                           eid16, rel, idxn, qodd, ordmax, E);
    qkvm_k<<<dim3(8, 24, 3), 256, 0, stream>>>(pFh, pFl, pWh, pWl, bq, bk, bv,
                                               qodd, kodd,
                                               pQh, pQl, pKh, pKl, pVh, pVl);
    scatter_k<<<EB, 256, 0, stream>>>(idxn, attr, rel, eid16, E);
    delta_k<<<(E * Hh + 255) / 256, 256, 0, stream>>>(idxn, rel, pQh, pQl, pKh, pKl,
                                                      qodd, kodd, delta8, E);
    flash8_k<<<dim3(SPLITS, 96, 8), 64, 0, stream>>>(pQh, pQl, pKh, pKl, pVh, pVl,
                                                     eid16, delta8, kodd, Opart, Lpart);
    combine_mp_k<<<96, 256, 0, stream>>>(Opart, Lpart, ordmax);
    decode_k<<<(Dd + 255) / 256, 256, 0, stream>>>(ordmax, outp);
}

// Round 11
// 200.121 us; speedup vs baseline: 1.1189x; 1.1189x over previous
//
#include <hip/hip_runtime.h>
#include <cmath>

// ---------------------------------------------------------------------------
// DistanceAwareMultiheadAttention  (N=1536, E=49152, D=512, H=8, DH=64)
//
// Round 11:
//  - REVERT r10's delta pack-gather (135MB FETCH, 62us: head-major pack
//    stride destroyed inter-head locality; 16B gathers paid full lines).
//    delta_k reads f32 Q/K rows again (coalesced); qkvm re-materializes
//    Q/K f32 (+6.3MB write, measured-good in r8).
//  - KEEP from r10: fused setup (sparse rel zero-init, no dense 9.4MB pass),
//    eid16, XCD-swizzled flash grid (s,qt,h), Opart/Lpart + combine,
//    ordered-uint atomicMax maxpool tail.
// ---------------------------------------------------------------------------

constexpr int Nn  = 1536;
constexpr int Dd  = 512;
constexpr int Hh  = 8;
constexpr int DHd = 64;
constexpr int SPLITS = 4;
constexpr float SCALE_F = 362.03867196751236f;   // 256*sqrt(2)
constexpr float M0 = 8.0f;                       // fixed softmax exp offset

typedef float f4 __attribute__((ext_vector_type(4)));
typedef int   i4 __attribute__((ext_vector_type(4)));
typedef unsigned short us4 __attribute__((ext_vector_type(4)));
typedef __attribute__((ext_vector_type(4))) float f32x4;
typedef __attribute__((ext_vector_type(8))) short bf16x8;

__device__ inline unsigned short bf16_rne(float x) {
    unsigned u = __float_as_uint(x);
    unsigned r = u + 0x7fff + ((u >> 16) & 1);
    return (unsigned short)(r >> 16);
}
__device__ inline float bf16_tof(unsigned short h) {
    return __uint_as_float(((unsigned)h) << 16);
}
__device__ inline unsigned f2ord(float x) {
    unsigned b = __float_as_uint(x);
    return (b & 0x80000000u) ? ~b : (b | 0x80000000u);
}

// ---- setup: feat/W pack + eid16 init + qodd/kodd/ordmax init + edge prep ---
__global__ __launch_bounds__(256) void setup_k(
    const float* __restrict__ feat,
    const float* __restrict__ Wq, const float* __restrict__ Wk, const float* __restrict__ Wv,
    const int* __restrict__ raw,
    unsigned short* __restrict__ pFh, unsigned short* __restrict__ pFl,
    unsigned short* __restrict__ pWh, unsigned short* __restrict__ pWl,
    unsigned short* __restrict__ eid16, float* __restrict__ rel,
    int* __restrict__ idxn, float* __restrict__ qkodd,
    unsigned* __restrict__ ordmax, int E)
{
    const int b = blockIdx.x, tid = threadIdx.x;
    if (b < 768) {
        int type = (b >= 384);
        int tg = (type ? (b - 384) : b) * 256 + tid;
        int L = tg & 63;
        int kc = (tg >> 6) & 15;
        int t10 = tg >> 10;
        const float* src;
        unsigned short *oh, *ol;
        int row, col;
        if (type == 0) {
            src = feat; oh = pFh; ol = pFl;
            row = t10 * 16 + (L & 15);
            col = kc * 32 + (L >> 4) * 8;
        } else {
            int z = t10 >> 5, nt = t10 & 31;
            src = (z == 0) ? Wq : (z == 1) ? Wk : Wv;
            oh = pWh; ol = pWl;
            row = nt * 16 + (L & 15);
            col = kc * 32 + (L >> 4) * 8;
        }
        f4 a = *(const f4*)(src + (size_t)row * Dd + col);
        f4 bb = *(const f4*)(src + (size_t)row * Dd + col + 4);
        float x[8];
        #pragma unroll
        for (int j = 0; j < 4; ++j) { x[j] = a[j]; x[4 + j] = bb[j]; }
        unsigned short hs[8], ls[8];
        #pragma unroll
        for (int j = 0; j < 8; ++j) {
            hs[j] = bf16_rne(x[j]);
            ls[j] = bf16_rne(x[j] - bf16_tof(hs[j]));
        }
        *(bf16x8*)(oh + (size_t)tg * 8) = *(bf16x8*)hs;
        *(bf16x8*)(ol + (size_t)tg * 8) = *(bf16x8*)ls;
    } else if (b < 3072) {
        size_t idx = (size_t)(b - 768) * 256 + tid;
        *(us4*)(eid16 + idx * 4) = (us4){0xFFFFu, 0xFFFFu, 0xFFFFu, 0xFFFFu};
    } else if (b < 3096) {
        size_t idx = (size_t)(b - 3072) * 256 + tid;
        *(f4*)(qkodd + idx * 4) = (f4){0.f, 0.f, 0.f, 0.f};
    } else if (b < 3098) {
        int idx = (b - 3096) * 256 + tid;
        ordmax[idx] = 0x007FFFFFu;  // encode(-inf)
    } else {
        int e = (b - 3098) * 256 + tid;
        if (e < E) {
            int acc = 0;
            #pragma unroll
            for (int i = 0; i < 16; ++i) acc |= raw[2 * i + 1];
            int s, t;
            if (acc == 0) { s = raw[2 * e]; t = raw[2 * (E + e)]; }   // int64
            else          { s = raw[e];     t = raw[E + e]; }          // int32
            idxn[e] = s; idxn[E + e] = t;
            rel[(size_t)s * Nn + t] = 0.f;   // zero only edge positions
        }
    }
}

// --------- QKV projection, MFMA, kc-pipelined, fused pack + odd-sums --------
__global__ __launch_bounds__(256) void qkvm_k(
    const unsigned short* __restrict__ pFh, const unsigned short* __restrict__ pFl,
    const unsigned short* __restrict__ pWh, const unsigned short* __restrict__ pWl,
    const float* __restrict__ bq, const float* __restrict__ bk, const float* __restrict__ bv,
    float* __restrict__ Qo, float* __restrict__ Ko,
    float* __restrict__ qodd, float* __restrict__ kodd,
    unsigned short* __restrict__ pQh, unsigned short* __restrict__ pQl,
    unsigned short* __restrict__ pKh, unsigned short* __restrict__ pKl,
    unsigned short* __restrict__ pVh, unsigned short* __restrict__ pVl)
{
    const int z = blockIdx.z;
    const float* __restrict__ bias = (z == 0) ? bq : (z == 1) ? bk : bv;
    const int tid = threadIdx.x;
    const int L = tid & 63, wv = tid >> 6;
    const int l15 = L & 15, quad = L >> 4;
    const int mt0 = blockIdx.y * 4 + (wv & 1) * 2;
    const int nt0 = blockIdx.x * 4 + (wv >> 1) * 2;
    __shared__ float lds[4][32][33];

    f32x4 acc[2][2];
    #pragma unroll
    for (int i = 0; i < 2; ++i)
        #pragma unroll
        for (int j = 0; j < 2; ++j) acc[i][j] = (f32x4){0.f, 0.f, 0.f, 0.f};

    bf16x8 AH[2][2], AL[2][2], BH[2][2], BL[2][2];
    auto loadset = [&](int buf, int kc) {
        #pragma unroll
        for (int i = 0; i < 2; ++i) {
            size_t ao = ((size_t)((mt0 + i) * 16 + kc)) * 512 + L * 8;
            AH[buf][i] = *(const bf16x8*)(pFh + ao);
            AL[buf][i] = *(const bf16x8*)(pFl + ao);
            size_t bo = ((size_t)((z * 32 + nt0 + i) * 16 + kc)) * 512 + L * 8;
            BH[buf][i] = *(const bf16x8*)(pWh + bo);
            BL[buf][i] = *(const bf16x8*)(pWl + bo);
        }
    };
    auto mfmaset = [&](int buf) {
        #pragma unroll
        for (int i = 0; i < 2; ++i)
            #pragma unroll
            for (int j = 0; j < 2; ++j) {
                f32x4 a = acc[i][j];
                a = __builtin_amdgcn_mfma_f32_16x16x32_bf16(AH[buf][i], BH[buf][j], a, 0, 0, 0);
                a = __builtin_amdgcn_mfma_f32_16x16x32_bf16(AH[buf][i], BL[buf][j], a, 0, 0, 0);
                a = __builtin_amdgcn_mfma_f32_16x16x32_bf16(AL[buf][i], BH[buf][j], a, 0, 0, 0);
                a = __builtin_amdgcn_mfma_f32_16x16x32_bf16(AL[buf][i], BL[buf][j], a, 0, 0, 0);
                acc[i][j] = a;
            }
    };

    loadset(0, 0);
    #pragma unroll
    for (int kc = 0; kc < 16; kc += 2) {
        loadset(1, kc + 1);
        mfmaset(0);
        if (kc + 2 < 16) loadset(0, kc + 2);
        mfmaset(1);
    }

    float o_[2][2][4];
    #pragma unroll
    for (int i = 0; i < 2; ++i)
        #pragma unroll
        for (int j = 0; j < 2; ++j) {
            float b = bias[(nt0 + j) * 16 + l15];
            #pragma unroll
            for (int reg = 0; reg < 4; ++reg) o_[i][j][reg] = acc[i][j][reg] + b;
        }
    const int h = blockIdx.x;   // cols [h*64, h*64+64) == head h
    if (z < 2) {
        float* __restrict__ outp = (z == 0) ? Qo : Ko;
        #pragma unroll
        for (int i = 0; i < 2; ++i) {
            int row0 = (mt0 + i) * 16 + quad * 4;
            #pragma unroll
            for (int j = 0; j < 2; ++j) {
                int col = (nt0 + j) * 16 + l15;
                #pragma unroll
                for (int reg = 0; reg < 4; ++reg)
                    outp[(size_t)(row0 + reg) * Dd + col] = o_[i][j][reg];
            }
        }
        // odd-col partial row sums -> qodd/kodd
        float* __restrict__ odst = (z == 0) ? qodd : kodd;
        #pragma unroll
        for (int i = 0; i < 2; ++i) {
            #pragma unroll
            for (int reg = 0; reg < 4; ++reg) {
                float v = (l15 & 1) ? (o_[i][0][reg] + o_[i][1][reg]) : 0.f;
                #pragma unroll
                for (int o = 1; o < 16; o <<= 1) v += __shfl_xor(v, o);
                if (l15 == 0) {
                    int row = (mt0 + i) * 16 + quad * 4 + reg;
                    atomicAdd(&odst[row * Hh + h], v);
                }
            }
        }
    }
    #pragma unroll
    for (int i = 0; i < 2; ++i)
        #pragma unroll
        for (int j = 0; j < 2; ++j)
            #pragma unroll
            for (int reg = 0; reg < 4; ++reg)
                lds[wv][i * 16 + quad * 4 + reg][j * 16 + l15] = o_[i][j][reg];
    // single-wave LDS round trip: DS pipe is in-order per wave, no barrier.

    if (z < 2) {
        unsigned short* __restrict__ oh = z ? pKh : pQh;
        unsigned short* __restrict__ ol = z ? pKl : pQl;
        const int kc = wv >> 1;
        const float sc = z ? 1.0f : 0.25f;      // Q pre-scaled (exact pow2)
        #pragma unroll
        for (int i = 0; i < 2; ++i) {
            float x[8]; unsigned short hs[8], ls[8];
            #pragma unroll
            for (int j2 = 0; j2 < 8; ++j2)
                x[j2] = lds[wv][i * 16 + l15][quad * 8 + j2] * sc;
            #pragma unroll
            for (int j2 = 0; j2 < 8; ++j2) {
                hs[j2] = bf16_rne(x[j2]);
                ls[j2] = bf16_rne(x[j2] - bf16_tof(hs[j2]));
            }
            size_t off = ((size_t)((h * 96 + mt0 + i) * 2 + kc)) * 512 + L * 8;
            *(bf16x8*)(oh + off) = *(bf16x8*)hs;
            *(bf16x8*)(ol + off) = *(bf16x8*)ls;
        }
    } else {
        const int rc = blockIdx.y * 2 + (wv & 1);
        #pragma unroll
        for (int dtl = 0; dtl < 2; ++dtl) {
            int dt = (wv >> 1) * 2 + dtl;
            float x[8]; unsigned short hs[8], ls[8];
            #pragma unroll
            for (int j2 = 0; j2 < 8; ++j2)
                x[j2] = lds[wv][quad * 8 + j2][dtl * 16 + l15];
            #pragma unroll
            for (int j2 = 0; j2 < 8; ++j2) {
                hs[j2] = bf16_rne(x[j2]);
                ls[j2] = bf16_rne(x[j2] - bf16_tof(hs[j2]));
            }
            size_t off = ((size_t)((h * 48 + rc) * 4 + dt)) * 512 + L * 8;
            *(bf16x8*)(pVh + off) = *(bf16x8*)hs;
            *(bf16x8*)(pVl + off) = *(bf16x8*)ls;
        }
    }
}

// --------------------------- scatter (idxn precomputed) ---------------------
__global__ __launch_bounds__(256) void scatter_k(
    const int* __restrict__ idxn, const float* __restrict__ attr,
    float* __restrict__ rel, unsigned short* __restrict__ eid16, int E)
{
    int e = blockIdx.x * 256 + threadIdx.x;
    if (e >= E) return;
    int s = idxn[e], t = idxn[E + e];
    size_t off = (size_t)s * Nn + t;
    atomicAdd(rel + off, attr[e] * SCALE_F);
    eid16[off] = (unsigned short)e;  // dup edges: same (s,t) -> same delta
}

// --------- per-edge, per-head corrections (coalesced f32 Q/K reads) ---------
__global__ __launch_bounds__(256) void delta_k(
    const int* __restrict__ idxn, const float* __restrict__ rel,
    const float* __restrict__ Q, const float* __restrict__ K,
    const float* __restrict__ qodd, const float* __restrict__ kodd,
    float* __restrict__ delta8, int E)
{
    int t = blockIdx.x * 256 + threadIdx.x;
    if (t >= E * Hh) return;
    int e = t >> 3, h = t & 7;
    int qi = idxn[e], ri = idxn[E + e];
    float x = rel[(size_t)qi * Nn + ri];
    const float* qrow = Q + (size_t)qi * Dd + h * DHd;
    const float* krow = K + (size_t)ri * Dd + h * DHd;
    float acc = 0.f;
    #pragma unroll
    for (int i = 0; i < 32; i += 2) {
        float dd0 = 0.15915494309189535f * __builtin_amdgcn_exp2f(-0.4152410118609203f * (float)i);
        float dd1 = 0.15915494309189535f * __builtin_amdgcn_exp2f(-0.4152410118609203f * (float)(i + 1));
        float r0 = x * dd0; r0 -= floorf(r0);
        float r1 = x * dd1; r1 -= floorf(r1);
        float s0 = __builtin_amdgcn_sinf(r0), c0 = __builtin_amdgcn_cosf(r0);
        float s1 = __builtin_amdgcn_sinf(r1), c1 = __builtin_amdgcn_cosf(r1);
        f4 q4 = *(const f4*)(qrow + 2 * i);
        f4 k4 = *(const f4*)(krow + 2 * i);
        acc += (q4[0] + k4[0]) * s0 + (q4[1] + k4[1]) * c0
             + (q4[2] + k4[2]) * s1 + (q4[3] + k4[3]) * c1;
    }
    delta8[(size_t)e * Hh + h] = 0.125f * (acc - qodd[qi * Hh + h] - kodd[ri * Hh + h]);
}

// -------- flash attention: no-max softmax, K dbuf, XCD-swizzled grid --------
// grid dim3(4,96,8): s=bx, qt=by, h=bz -> linear id = h*384 + qt*4 + s;
// 384 % 8 == 0 puts all 8 heads of a (qt,s) in one id%8 XCD class so eid16
// rows are fetched once per XCD, not 8x.
__global__ __launch_bounds__(64, 3) void flash8_k(
    const unsigned short* __restrict__ pQh, const unsigned short* __restrict__ pQl,
    const unsigned short* __restrict__ pKh, const unsigned short* __restrict__ pKl,
    const unsigned short* __restrict__ pVh, const unsigned short* __restrict__ pVl,
    const unsigned short* __restrict__ eid16, const float* __restrict__ delta8,
    const float* __restrict__ kodd,
    float* __restrict__ Opart, float* __restrict__ Lpart)
{
    const int s = blockIdx.x, qt = blockIdx.y, h = blockIdx.z;
    const int L = threadIdx.x, quad = L >> 4, l15 = L & 15;
    const int q0 = qt * 16;
    __shared__ unsigned short phi[16][80];
    __shared__ unsigned short plo[16][80];

    bf16x8 qh[2], ql[2];
    #pragma unroll
    for (int kc = 0; kc < 2; ++kc) {
        size_t off = ((size_t)((h * 96 + qt) * 2 + kc)) * 512 + L * 8;
        qh[kc] = *(const bf16x8*)(pQh + off);
        ql[kc] = *(const bf16x8*)(pQl + off);
    }

    f32x4 O[4];
    float lsum[4];
    #pragma unroll
    for (int r = 0; r < 4; ++r) { lsum[r] = 0.f; O[r] = (f32x4){0.f, 0.f, 0.f, 0.f}; }

    const int NT = 24 / SPLITS;
    const int Tbase = s * NT;

    bf16x8 kh0[4], kh1[4], kl0[4], kl1[4];
    {
        const int r0 = Tbase * 64;
        #pragma unroll
        for (int nt = 0; nt < 4; ++nt) {
            size_t b0 = ((size_t)((h * 96 + (r0 >> 4) + nt) * 2)) * 512 + L * 8;
            kh0[nt] = *(const bf16x8*)(pKh + b0);
            kh1[nt] = *(const bf16x8*)(pKh + b0 + 512);
            kl0[nt] = *(const bf16x8*)(pKl + b0);
            kl1[nt] = *(const bf16x8*)(pKl + b0 + 512);
        }
    }

    float kvcur[4], dcur[16];
    {
        const int r0 = Tbase * 64;
        int ecur[16];
        #pragma unroll
        for (int nt = 0; nt < 4; ++nt) {
            kvcur[nt] = 0.125f * kodd[(size_t)(r0 + nt * 16 + l15) * Hh + h];
            #pragma unroll
            for (int reg = 0; reg < 4; ++reg) {
                unsigned short uv = eid16[(size_t)(q0 + quad * 4 + reg) * Nn + r0 + nt * 16 + l15];
                ecur[nt * 4 + reg] = (uv == 0xFFFFu) ? -1 : (int)uv;
            }
        }
        #pragma unroll
        for (int i = 0; i < 16; ++i) {
            int e = ecur[i];
            float d = delta8[(size_t)(e < 0 ? 0 : e) * Hh + h];
            dcur[i] = (e >= 0) ? d : 0.f;
        }
    }

    for (int T = 0; T < NT; ++T) {
        const int r0 = (Tbase + T) * 64;
        const bool more = (T + 1 < NT);

        int   enxt[16];
        float kvnxt[4];
        if (more) {
            const int r1 = r0 + 64;
            #pragma unroll
            for (int nt = 0; nt < 4; ++nt) {
                kvnxt[nt] = 0.125f * kodd[(size_t)(r1 + nt * 16 + l15) * Hh + h];
                #pragma unroll
                for (int reg = 0; reg < 4; ++reg) {
                    unsigned short uv = eid16[(size_t)(q0 + quad * 4 + reg) * Nn + r1 + nt * 16 + l15];
                    enxt[nt * 4 + reg] = (uv == 0xFFFFu) ? -1 : (int)uv;
                }
            }
        }

        bf16x8 vh0[4], vh1[4], vl0[4], vl1[4];
        #pragma unroll
        for (int dt = 0; dt < 4; ++dt) {
            size_t vb = ((size_t)((h * 48 + (r0 >> 5)) * 4 + dt)) * 512 + L * 8;
            vh0[dt] = *(const bf16x8*)(pVh + vb);
            vh1[dt] = *(const bf16x8*)(pVh + vb + 2048);
            vl0[dt] = *(const bf16x8*)(pVl + vb);
            vl1[dt] = *(const bf16x8*)(pVl + vb + 2048);
        }

        f32x4 S[4];
        #pragma unroll
        for (int nt = 0; nt < 4; ++nt) {
            f32x4 a = {0.f, 0.f, 0.f, 0.f};
            a = __builtin_amdgcn_mfma_f32_16x16x32_bf16(qh[0], kh0[nt], a, 0, 0, 0);
            a = __builtin_amdgcn_mfma_f32_16x16x32_bf16(qh[1], kh1[nt], a, 0, 0, 0);
            a = __builtin_amdgcn_mfma_f32_16x16x32_bf16(qh[0], kl0[nt], a, 0, 0, 0);
            a = __builtin_amdgcn_mfma_f32_16x16x32_bf16(qh[1], kl1[nt], a, 0, 0, 0);
            a = __builtin_amdgcn_mfma_f32_16x16x32_bf16(ql[0], kh0[nt], a, 0, 0, 0);
            a = __builtin_amdgcn_mfma_f32_16x16x32_bf16(ql[1], kh1[nt], a, 0, 0, 0);
            S[nt] = a;
        }

        if (more) {
            const int r1 = r0 + 64;
            #pragma unroll
            for (int nt = 0; nt < 4; ++nt) {
                size_t b0 = ((size_t)((h * 96 + (r1 >> 4) + nt) * 2)) * 512 + L * 8;
                kh0[nt] = *(const bf16x8*)(pKh + b0);
                kh1[nt] = *(const bf16x8*)(pKh + b0 + 512);
                kl0[nt] = *(const bf16x8*)(pKl + b0);
                kl1[nt] = *(const bf16x8*)(pKl + b0 + 512);
            }
        }

        #pragma unroll
        for (int reg = 0; reg < 4; ++reg) {
            float p[4];
            #pragma unroll
            for (int nt = 0; nt < 4; ++nt) {
                p[nt] = __expf(S[nt][reg] + kvcur[nt] + dcur[nt * 4 + reg] - M0);
                lsum[reg] += p[nt];
                unsigned short hi = bf16_rne(p[nt]);
                phi[quad * 4 + reg][nt * 16 + l15] = hi;
                plo[quad * 4 + reg][nt * 16 + l15] = bf16_rne(p[nt] - bf16_tof(hi));
            }
        }

        bf16x8 ph[2], pl[2];
        #pragma unroll
        for (int kc2 = 0; kc2 < 2; ++kc2) {
            ph[kc2] = *(const bf16x8*)&phi[l15][kc2 * 32 + quad * 8];
            pl[kc2] = *(const bf16x8*)&plo[l15][kc2 * 32 + quad * 8];
        }

        #pragma unroll
        for (int dt = 0; dt < 4; ++dt) {
            f32x4 a = O[dt];
            a = __builtin_amdgcn_mfma_f32_16x16x32_bf16(ph[0], vh0[dt], a, 0, 0, 0);
            a = __builtin_amdgcn_mfma_f32_16x16x32_bf16(ph[1], vh1[dt], a, 0, 0, 0);
            a = __builtin_amdgcn_mfma_f32_16x16x32_bf16(ph[0], vl0[dt], a, 0, 0, 0);
            a = __builtin_amdgcn_mfma_f32_16x16x32_bf16(ph[1], vl1[dt], a, 0, 0, 0);
            a = __builtin_amdgcn_mfma_f32_16x16x32_bf16(pl[0], vh0[dt], a, 0, 0, 0);
            a = __builtin_amdgcn_mfma_f32_16x16x32_bf16(pl[1], vh1[dt], a, 0, 0, 0);
            O[dt] = a;
        }

        if (more) {
            #pragma unroll
            for (int i = 0; i < 16; ++i) {
                int e = enxt[i];
                float d = delta8[(size_t)(e < 0 ? 0 : e) * Hh + h];
                dcur[i] = (e >= 0) ? d : 0.f;
            }
            #pragma unroll
            for (int nt = 0; nt < 4; ++nt) kvcur[nt] = kvnxt[nt];
        }
    }

    #pragma unroll
    for (int reg = 0; reg < 4; ++reg) {
        #pragma unroll
        for (int o = 1; o < 16; o <<= 1) lsum[reg] += __shfl_xor(lsum[reg], o);
    }

    #pragma unroll
    for (int dt = 0; dt < 4; ++dt)
        #pragma unroll
        for (int reg = 0; reg < 4; ++reg)
            Opart[((size_t)(s * Hh + h) * Nn + q0 + quad * 4 + reg) * 64 + dt * 16 + l15] = O[dt][reg];
    if (l15 == 0) {
        #pragma unroll
        for (int reg = 0; reg < 4; ++reg)
            Lpart[(size_t)(s * Hh + h) * Nn + q0 + quad * 4 + reg] = lsum[reg];
    }
}

// ------- split-K combine + maxpool via ordered-uint atomicMax (512 slots) ---
__global__ __launch_bounds__(256) void combine_mp_k(
    const float* __restrict__ Opart, const float* __restrict__ Lpart,
    unsigned* __restrict__ ordmax)
{
    const int b = blockIdx.x;
    const int t = threadIdx.x;
    const int cg = (t & 127) * 4;
    const int h = cg >> 6, d = cg & 63;
    const int rh = t >> 7;
    f4 mx = {-3.0e38f, -3.0e38f, -3.0e38f, -3.0e38f};
    for (int r = 0; r < 8; ++r) {
        int q = b * 16 + rh * 8 + r;
        float l = 0.f;
        f4 o = {0.f, 0.f, 0.f, 0.f};
        #pragma unroll
        for (int s2 = 0; s2 < SPLITS; ++s2) {
            l += Lpart[(size_t)(s2 * Hh + h) * Nn + q];
            f4 ov = *(const f4*)(Opart + ((size_t)(s2 * Hh + h) * Nn + q) * 64 + d);
            #pragma unroll
            for (int c = 0; c < 4; ++c) o[c] += ov[c];
        }
        float inv = 1.0f / l;
        #pragma unroll
        for (int c = 0; c < 4; ++c) mx[c] = fmaxf(mx[c], o[c] * inv);
    }
    #pragma unroll
    for (int c = 0; c < 4; ++c) atomicMax(&ordmax[cg + c], f2ord(mx[c]));
}

__global__ void decode_k(const unsigned* __restrict__ ordmax, float* __restrict__ outp)
{
    int t = blockIdx.x * 256 + threadIdx.x;
    if (t >= Dd) return;
    unsigned u = ordmax[t];
    outp[t] = (u & 0x80000000u) ? __uint_as_float(u ^ 0x80000000u) : __uint_as_float(~u);
}

// ---------------------------------------------------------------------------
extern "C" void kernel_launch(void* const* d_in, const int* in_sizes, int n_in,
                              void* d_out, int out_size, void* d_ws, size_t ws_size,
                              hipStream_t stream)
{
    const float* feat   = (const float*)d_in[0];
    const int*   rawidx = (const int*)d_in[1];
    const float* attr   = (const float*)d_in[2];
    const float* Wq = (const float*)d_in[4];
    const float* bq = (const float*)d_in[5];
    const float* Wk = (const float*)d_in[6];
    const float* bk = (const float*)d_in[7];
    const float* Wv = (const float*)d_in[8];
    const float* bv = (const float*)d_in[9];
    float* outp = (float*)d_out;
    const int E = in_sizes[2];
    const int EB = (E + 255) / 256;

    const size_t ND_ = (size_t)Nn * Dd;            // 786432
    const size_t NN_ = (size_t)Nn * Nn;            // 2359296
    const size_t PK_ = (size_t)Hh * 96 * 2 * 512;  // 786432 shorts per pack
    // Prefix dead by flash: Q,K f32 (1,572,864 f) + pF/pW packs (1,572,864
    // f-equiv) + rel (2,359,296 f) = 5,505,024 f >= Opart (3,145,728 f).
    float* ws = (float*)d_ws;
    float* Q  = ws;                                 // 786432 f
    float* K  = Q + ND_;                            // 786432 f
    unsigned short* pFh = (unsigned short*)(K + ND_);   // 4 x 786432 shorts
    unsigned short* pFl = pFh + PK_;
    unsigned short* pWh = pFl + PK_;
    unsigned short* pWl = pWh + PK_;
    float* rel = (float*)(pWl + PK_);               // 2359296 f (edge-sparse)
    unsigned short* eid16 = (unsigned short*)(rel + NN_);  // 2359296 shorts
    float* delta8 = (float*)(eid16 + NN_);          // E*Hh f
    float* qodd  = delta8 + (size_t)E * Hh;         // Nn*Hh f (zeroed w/ kodd)
    float* kodd  = qodd + (size_t)Nn * Hh;          // Nn*Hh f
    int*   idxn  = (int*)(kodd + (size_t)Nn * Hh);  // 2E ints
    unsigned short* pQh = (unsigned short*)(idxn + 2 * E);
    unsigned short* pQl = pQh + PK_;
    unsigned short* pKh = pQl + PK_;
    unsigned short* pKl = pKh + PK_;
    unsigned short* pVh = pKl + PK_;
    unsigned short* pVl = pVh + PK_;
    float* Lpart = (float*)(pVl + PK_);             // SPLITS*Hh*Nn f
    unsigned* ordmax = (unsigned*)(Lpart + (size_t)SPLITS * Hh * Nn);  // 512 u
    float* Opart = ws;   // overlays Q,K,pF/pW,rel (dead by flash time)

    setup_k<<<3098 + EB, 256, 0, stream>>>(feat, Wq, Wk, Wv, rawidx,
                                           pFh, pFl, pWh, pWl,
                                           eid16, rel, idxn, qodd, ordmax, E);
    qkvm_k<<<dim3(8, 24, 3), 256, 0, stream>>>(pFh, pFl, pWh, pWl, bq, bk, bv,
                                               Q, K, qodd, kodd,
                                               pQh, pQl, pKh, pKl, pVh, pVl);
    scatter_k<<<EB, 256, 0, stream>>>(idxn, attr, rel, eid16, E);
    delta_k<<<(E * Hh + 255) / 256, 256, 0, stream>>>(idxn, rel, Q, K,
                                                      qodd, kodd, delta8, E);
    flash8_k<<<dim3(SPLITS, 96, 8), 64, 0, stream>>>(pQh, pQl, pKh, pKl, pVh, pVl,
                                                     eid16, delta8, kodd, Opart, Lpart);
    combine_mp_k<<<96, 256, 0, stream>>>(Opart, Lpart, ordmax);
    decode_k<<<(Dd + 255) / 256, 256, 0, stream>>>(ordmax, outp);
}